// Round 6
// baseline (102.510 us; speedup 1.0000x reference)
//
#include <hip/hip_runtime.h>
#include <math.h>

// DILATE / soft-DTW — round 18: r17 + PINNED-ORDER inline-asm chain interleave.
// r17 post-mortem: 380 cyc/step wall vs ~130-200 of real work; one wave per
// SIMD (512 problems = 512 waves on 1024 SIMDs) means every dependency stall
// is exposed, and VGPR=32 (budget 512) shows the scheduler serialized the 6
// independent chains (3 R + 3 G) to minimize pressure instead of interleaving.
// r18: force the interleave with VOLATILE asm for the chain-critical ops only:
//   3x v_min3_f32  ->  9x v_exp_f32 (cell-grouped)  ->  log/rcp per cell.
// Volatile asms keep strict relative order; plain C ops (subs/fmas/rotates)
// remain free for the compiler to slot into the trans shadows. The emitted
// operations and their per-cell operand order are IDENTICAL to r17 (builtins
// already lower to v_exp_f32/v_log_f32/v_rcp_f32; nested fminf == v_min3)
// -> absmax 0.0. P-prefetch becomes explicit ds_read_b32 asm + an
// operand-tied s_waitcnt at block end ("+v" ties prevent any use hoisting
// above the wait — rule-18 safe).
// Diagnostic round: if neutral, the trans unit's wave64 occupancy is the
// floor -> r19 cuts trans count.
// Kept: systolic 3-rows/lane decomposition (54 lanes, 319 steps, no ring,
// no barriers), C2-domain carry (GLN2*C2==1), subtract-form exp args (r5),
// DPP old-injection for the row-band seam, 512 x 64 launch.

#define NN     160
#define BC_TOT 512
#define B_SZ   64
#define C_SZ   8
#define BIGC2  1e12f              // border sentinel in C2 domain
#define SC2    12.01122405f       // sqrt(C2), C2 = 144.269504089
#define GLN2   0.0069314718056f   // gamma*ln2 == 1/C2

// lane i <- lane i-1; lane 0 <- old (bound_ctrl=false). Standard scan idiom.
__device__ __forceinline__ float dpp_up1_inj(float old, float x) {
    int oi = __builtin_bit_cast(int, old);
    int xi = __builtin_bit_cast(int, x);
    return __builtin_bit_cast(float,
        __builtin_amdgcn_update_dpp(oi, xi, 0x138, 0xF, 0xF, false)); // wave_shr1
}

// One wall-step: 3 cells (sub-rows 0..2). Chain-critical ops pinned via
// volatile asm (strict relative order); the rest is free-scheduled C.
// Values and per-cell op order identical to r17 -> bit-identical results.
#define STEP(PV0) do {                                                        \
    float mn0, mn1, mn2;                                                      \
    asm volatile("v_min3_f32 %0, %1, %2, %3"                                  \
                 : "=v"(mn0) : "v"(b0), "v"(a0), "v"(r0));                    \
    asm volatile("v_min3_f32 %0, %1, %2, %3"                                  \
                 : "=v"(mn1) : "v"(b1), "v"(a1), "v"(r1));                    \
    asm volatile("v_min3_f32 %0, %1, %2, %3"                                  \
                 : "=v"(mn2) : "v"(b2), "v"(a2), "v"(r2));                    \
    const float xd0 = mn0 - b0, xv0 = mn0 - a0, xh0 = mn0 - r0;               \
    const float xd1 = mn1 - b1, xv1 = mn1 - a1, xh1 = mn1 - r1;               \
    const float xd2 = mn2 - b2, xv2 = mn2 - a2, xh2 = mn2 - r2;               \
    float ed0, ev0, eh0, ed1, ev1, eh1, ed2, ev2, eh2;                        \
    asm volatile("v_exp_f32 %0, %1" : "=v"(ed0) : "v"(xd0));                  \
    asm volatile("v_exp_f32 %0, %1" : "=v"(ev0) : "v"(xv0));                  \
    asm volatile("v_exp_f32 %0, %1" : "=v"(eh0) : "v"(xh0));                  \
    asm volatile("v_exp_f32 %0, %1" : "=v"(ed1) : "v"(xd1));                  \
    asm volatile("v_exp_f32 %0, %1" : "=v"(ev1) : "v"(xv1));                  \
    asm volatile("v_exp_f32 %0, %1" : "=v"(eh1) : "v"(xh1));                  \
    asm volatile("v_exp_f32 %0, %1" : "=v"(ed2) : "v"(xd2));                  \
    asm volatile("v_exp_f32 %0, %1" : "=v"(ev2) : "v"(xv2));                  \
    asm volatile("v_exp_f32 %0, %1" : "=v"(eh2) : "v"(xh2));                  \
    const float ss0 = (ed0 + ev0) + eh0;   /* >= 1 */                         \
    const float ss1 = (ed1 + ev1) + eh1;                                      \
    const float ss2 = (ed2 + ev2) + eh2;                                      \
    float lg0, rs0, lg1, rs1, lg2, rs2;                                       \
    asm volatile("v_log_f32 %0, %1" : "=v"(lg0) : "v"(ss0));                  \
    asm volatile("v_rcp_f32 %0, %1" : "=v"(rs0) : "v"(ss0));                  \
    asm volatile("v_log_f32 %0, %1" : "=v"(lg1) : "v"(ss1));                  \
    asm volatile("v_rcp_f32 %0, %1" : "=v"(rs1) : "v"(ss1));                  \
    asm volatile("v_log_f32 %0, %1" : "=v"(lg2) : "v"(ss2));                  \
    asm volatile("v_rcp_f32 %0, %1" : "=v"(rs2) : "v"(ss2));                  \
    const float dt0 = trS0 - (PV0);                                           \
    const float dt1 = trS1 - pva;                                             \
    const float dt2 = trS2 - pvb;                                             \
    const float n0 = __builtin_fmaf(dt0, dt0, mn0) - lg0;                     \
    const float n1 = __builtin_fmaf(dt1, dt1, mn1) - lg1;                     \
    const float n2 = __builtin_fmaf(dt2, dt2, mn2) - lg2;                     \
    const float nm0 = __builtin_fmaf(ed0, bd0,                                \
                      __builtin_fmaf(ev0, ad0, eh0 * g0));                    \
    const float nm1 = __builtin_fmaf(ed1, bd1,                                \
                      __builtin_fmaf(ev1, ad1, eh1 * g1));                    \
    const float nm2 = __builtin_fmaf(ed2, bd2,                                \
                      __builtin_fmaf(ev2, ad2, eh2 * g2));                    \
    const float dj1 = dj0 - 2.0f, dj2 = dj0 - 4.0f;                           \
    const float nd0 = __builtin_fmaf(nm0, rs0, dj0 * dj0);                    \
    const float nd1 = __builtin_fmaf(nm1, rs1, dj1 * dj1);                    \
    const float nd2 = __builtin_fmaf(nm2, rs2, dj2 * dj2);                    \
    b2 = a2;  bd2 = ad2;  a2 = n1;  ad2 = nd1;                                \
    b1 = a1;  bd1 = ad1;  a1 = n0;  ad1 = nd0;                                \
    b0 = a0;  bd0 = ad0;                                                      \
    a0  = dpp_up1_inj(BIGC2, n2);   /* lane0 <- R[0][j] = border */           \
    ad0 = dpp_up1_inj(0.0f,  nd2);  /* lane0 <- Rdot[0][j] = 0    */          \
    r0 = n0; r1 = n1; r2 = n2;                                                \
    g0 = nd0; g1 = nd1; g2 = nd2;                                             \
    pvb = pva; pva = (PV0);                                                   \
    dj0 += 1.0f;                                                              \
} while (0)

__global__ __launch_bounds__(64, 1)
void dtw_fwd_kernel(const float* __restrict__ input,
                    const float* __restrict__ target,
                    float* __restrict__ sdtw,    // BC_TOT: R[N,N]
                    float* __restrict__ wlt)     // BC_TOT: Rdot[N,N]/N^2
{
    const int k    = blockIdx.x;
    const int lane = threadIdx.x;                // 0..63, one wave

    __shared__ __align__(16) float Pp[512];      // Pp[x] = pg[x-192]*SC2, pad 0

    const float* tg = target + (size_t)k * NN;
    const float* pg = input  + (size_t)k * NN;
    #pragma unroll
    for (int x0 = 0; x0 < 512; x0 += 64) {
        const int x = x0 + lane;
        const int v = x - 192;
        Pp[x] = ((unsigned)v < (unsigned)NN) ? pg[v] * SC2 : 0.0f;
    }
    // T values for the lane's 3 rows (i = 3l+1..3l+3 -> T[3l+s])
    const int r3 = 3 * lane;
    const float trS0 = (r3 + 0 < NN) ? tg[r3 + 0] * SC2 : 0.0f;
    const float trS1 = (r3 + 1 < NN) ? tg[r3 + 1] * SC2 : 0.0f;
    const float trS2 = (r3 + 2 < NN) ? tg[r3 + 2] * SC2 : 0.0f;
    // single wave: LDS write->read needs only a wait, no barrier
    __asm__ __volatile__("" ::: "memory");
    __builtin_amdgcn_s_waitcnt(0xC07F);          // lgkmcnt(0)
    __asm__ __volatile__("" ::: "memory");

    // rolling state (C2 domain): r*/g* = left (R, Rdot); a*/ad* = up;
    // b*/bd* = diag. Inits are borders; lane0 b0 = R[0][0] = 0 exact.
    float r0 = BIGC2, r1 = BIGC2, r2 = BIGC2;
    float g0 = 0.0f,  g1 = 0.0f,  g2 = 0.0f;
    float a0 = BIGC2, a1 = BIGC2, a2 = BIGC2;
    float ad0 = 0.0f, ad1 = 0.0f, ad2 = 0.0f;
    float b0 = (lane == 0) ? 0.0f : BIGC2;
    float b1 = BIGC2, b2 = BIGC2;
    float bd0 = 0.0f, bd1 = 0.0f, bd2 = 0.0f;

    float pva = 0.0f, pvb = 0.0f;                // pv of steps t-1, t-2
    float dj0 = (float)(-6 * lane);              // (j - i) for s=0 at t=0

    const int pb = 192 - r3;                     // pidx(t) = pb + t
    // P prefetch: 4-step register buffer, software-pipelined one block ahead.
    float pf0 = Pp[pb + 0], pf1 = Pp[pb + 1], pf2 = Pp[pb + 2], pf3 = Pp[pb + 3];
    const unsigned pByte = (unsigned)(unsigned long long)&Pp[pb]; // LDS byte addr

    // 79 blocks of 4 steps = 316, + 3 epilogue = 319 steps (t = 0..318)
    float q0, q1, q2, q3;
    for (int tb = 0; tb < 79; ++tb) {
        const unsigned av = pByte + 16u * (unsigned)tb + 16u;  // Pp[pb+4tb+4]
        asm volatile("ds_read_b32 %0, %1 offset:0"  : "=v"(q0) : "v"(av) : "memory");
        asm volatile("ds_read_b32 %0, %1 offset:4"  : "=v"(q1) : "v"(av) : "memory");
        asm volatile("ds_read_b32 %0, %1 offset:8"  : "=v"(q2) : "v"(av) : "memory");
        asm volatile("ds_read_b32 %0, %1 offset:12" : "=v"(q3) : "v"(av) : "memory");
        STEP(pf0); STEP(pf1); STEP(pf2); STEP(pf3);
        // operand-tied wait: no use of q* can be hoisted above this.
        asm volatile("s_waitcnt lgkmcnt(0)"
                     : "+v"(q0), "+v"(q1), "+v"(q2), "+v"(q3));
        pf0 = q0; pf1 = q1; pf2 = q2; pf3 = q3;
    }
    STEP(pf0); STEP(pf1); STEP(pf2);             // t = 316, 317, 318

    // lane 53, s=0 is row 160; its last computed cell (t=318) is (160,160),
    // still in r0/g0 after the final rotation.
    if (lane == 53) {
        sdtw[k] = r0 * GLN2;                     // back to normal domain
        wlt[k]  = g0 * (1.0f / (NN * NN));
    }
}

// final reduction: per-batch means + scalar loss. One wave (64 threads = B).
__global__ __launch_bounds__(64)
void finalize_kernel(const float* __restrict__ sdtw,
                     const float* __restrict__ wlt,
                     float* __restrict__ out)
{
    const int b = threadIdx.x;   // 0..63
    float ls = 0.0f, lt = 0.0f;
    #pragma unroll
    for (int c = 0; c < C_SZ; ++c) {
        ls += sdtw[b * C_SZ + c];
        lt += wlt[b * C_SZ + c];
    }
    ls *= (1.0f / C_SZ);
    lt *= (1.0f / C_SZ);
    out[1 + b]        = ls;
    out[1 + B_SZ + b] = lt;
    float v = 0.5f * ls + 0.5f * lt;
    #pragma unroll
    for (int o = 32; o > 0; o >>= 1) v += __shfl_down(v, o);
    if (b == 0) out[0] = v * (1.0f / B_SZ);
}

extern "C" void kernel_launch(void* const* d_in, const int* in_sizes, int n_in,
                              void* d_out, int out_size, void* d_ws, size_t ws_size,
                              hipStream_t stream) {
    const float* input  = (const float*)d_in[0];
    const float* target = (const float*)d_in[1];
    float* out = (float*)d_out;   // 129 floats

    float* sdtw = (float*)d_ws;                 // 512 floats
    float* wlt  = sdtw + BC_TOT;                // 512 floats

    dtw_fwd_kernel<<<BC_TOT, 64, 0, stream>>>(input, target, sdtw, wlt);
    finalize_kernel<<<1, 64, 0, stream>>>(sdtw, wlt, out);
}